// Round 1
// baseline (335.550 us; speedup 1.0000x reference)
//
#include <hip/hip_runtime.h>

// Problem constants
constexpr int BB = 16;     // batch
constexpr int CC = 512;    // channels
constexpr int PP = 32;     // clusters
constexpr int NN = 4096;   // H*W

// ---------------------------------------------------------------------------
// prep: beta = sigmoid(sf), rbeta = 1/beta, csq[p] = sum_c centers[p][c]^2
// grid 32 (one block per p), block 64 (one wave)
// ---------------------------------------------------------------------------
__global__ __launch_bounds__(64) void prep_kernel(
    const float* __restrict__ w, const float* __restrict__ sf,
    float* __restrict__ beta, float* __restrict__ rbeta,
    float* __restrict__ csq) {
  int p = blockIdx.x;
  int t = threadIdx.x;
  float s = 0.f;
  for (int i = t; i < CC; i += 64) {
    float v = w[p * CC + i];
    s = fmaf(v, v, s);
  }
#pragma unroll
  for (int off = 32; off; off >>= 1) s += __shfl_down(s, off);
  if (t == 0) {
    csq[p] = s;
    float e = __expf(-sf[p]);      // rbeta = 1 + e^-s ; beta = 1/(1+e^-s)
    rbeta[p] = 1.f + e;
    beta[p] = 1.f / (1.f + e);
  }
}

// ---------------------------------------------------------------------------
// assign: per pixel, cx[p] = <centers_p, x>, logits, softmax over P.
// grid = B*16 = 256 blocks, block = 256 threads, 1 pixel per thread.
// centers staged in 64KB LDS, broadcast float4 reads.
// ---------------------------------------------------------------------------
__global__ __launch_bounds__(256) void assign_kernel(
    const float* __restrict__ x, const float* __restrict__ w,
    const float* __restrict__ rbeta, const float* __restrict__ csq,
    float* __restrict__ assign_out) {
  __shared__ float cent[PP * CC];  // 64 KB
  int tid = threadIdx.x;
  for (int i = tid; i < PP * CC; i += 256) cent[i] = w[i];
  __syncthreads();

  int b = blockIdx.x >> 4;
  int n = ((blockIdx.x & 15) << 8) + tid;
  const float* xp = x + (size_t)b * CC * NN + n;

  float cx[PP];
#pragma unroll
  for (int p = 0; p < PP; ++p) cx[p] = 0.f;
  float xsq = 0.f;

#pragma unroll 2
  for (int c = 0; c < CC; c += 4) {
    float x0 = xp[(size_t)(c + 0) * NN];
    float x1 = xp[(size_t)(c + 1) * NN];
    float x2 = xp[(size_t)(c + 2) * NN];
    float x3 = xp[(size_t)(c + 3) * NN];
    xsq = fmaf(x0, x0, fmaf(x1, x1, fmaf(x2, x2, fmaf(x3, x3, xsq))));
#pragma unroll
    for (int p = 0; p < PP; ++p) {
      const float4 cc4 = *(const float4*)&cent[p * CC + c];
      cx[p] = fmaf(cc4.x, x0,
              fmaf(cc4.y, x1, fmaf(cc4.z, x2, fmaf(cc4.w, x3, cx[p]))));
    }
  }

  // logits = min(2cx - xsq - csq, 0) / beta ; softmax over p
  float m = -3.4e38f;
#pragma unroll
  for (int p = 0; p < PP; ++p) {
    float l = fminf(2.f * cx[p] - xsq - csq[p], 0.f) * rbeta[p];
    cx[p] = l;
    m = fmaxf(m, l);
  }
  float s = 0.f;
#pragma unroll
  for (int p = 0; p < PP; ++p) {
    float e = __expf(cx[p] - m);
    cx[p] = e;
    s += e;
  }
  float inv = 1.f / s;
  float* ao = assign_out + (size_t)b * PP * NN + n;
#pragma unroll
  for (int p = 0; p < PP; ++p) ao[(size_t)p * NN] = cx[p] * inv;
}

// ---------------------------------------------------------------------------
// sum_ass: sum over n of assign, clipped below at 1e-5.
// one wave per (b,p): 512 waves -> 128 blocks of 256 threads.
// ---------------------------------------------------------------------------
__global__ __launch_bounds__(256) void sum_ass_kernel(
    const float* __restrict__ assign, float* __restrict__ sum_ass) {
  int wid = blockIdx.x * 4 + (threadIdx.x >> 6);  // 0..511
  int lane = threadIdx.x & 63;
  const float4* ap = (const float4*)(assign + (size_t)wid * NN);
  float s = 0.f;
#pragma unroll
  for (int i = 0; i < 16; ++i) {
    float4 v = ap[i * 64 + lane];
    s += (v.x + v.y) + (v.z + v.w);
  }
#pragma unroll
  for (int off = 32; off; off >>= 1) s += __shfl_down(s, off);
  if (lane == 0) sum_ass[wid] = fmaxf(s, 1e-5f);
}

// ---------------------------------------------------------------------------
// qx[b][p][c] = sum_n assign[b][p][n] * x[b][c][n]
// one wave per (b,c): grid (C/4, B), block 256 (4 waves).
// ---------------------------------------------------------------------------
__global__ __launch_bounds__(256) void qx_kernel(
    const float* __restrict__ x, const float* __restrict__ assign,
    float* __restrict__ qx) {
  int wave = threadIdx.x >> 6, lane = threadIdx.x & 63;
  int c = blockIdx.x * 4 + wave;
  int b = blockIdx.y;
  const float4* xp = (const float4*)(x + ((size_t)b * CC + c) * NN);
  const float* ap = assign + (size_t)b * PP * NN;

  float acc[PP];
#pragma unroll
  for (int p = 0; p < PP; ++p) acc[p] = 0.f;

#pragma unroll 2
  for (int it = 0; it < 16; ++it) {
    int i = it * 64 + lane;
    float4 xv = xp[i];
#pragma unroll
    for (int p = 0; p < PP; ++p) {
      float4 av = ((const float4*)(ap + (size_t)p * NN))[i];
      acc[p] = fmaf(av.x, xv.x,
               fmaf(av.y, xv.y, fmaf(av.z, xv.z, fmaf(av.w, xv.w, acc[p]))));
    }
  }
#pragma unroll
  for (int p = 0; p < PP; ++p) {
    float v = acc[p];
#pragma unroll
    for (int off = 32; off; off >>= 1) v += __shfl_down(v, off);
    if (lane == 0) qx[((size_t)b * PP + p) * CC + c] = v;
  }
}

// ---------------------------------------------------------------------------
// finalize: out = (qx/sum_ass - centers)/sigma ; L2-normalize over c;
// write transposed out_t[b][c][p]. block per (b,p), 256 threads, 2 c each.
// ---------------------------------------------------------------------------
__global__ __launch_bounds__(256) void finalize_kernel(
    const float* __restrict__ qx, const float* __restrict__ w,
    const float* __restrict__ beta, const float* __restrict__ sum_ass,
    float* __restrict__ out_t) {
  int b = blockIdx.x >> 5;
  int p = blockIdx.x & 31;
  int tid = threadIdx.x;
  int wave = tid >> 6, lane = tid & 63;

  float inv_sa = 1.f / sum_ass[b * PP + p];
  float rsig = rsqrtf(0.5f * beta[p]);  // 1/sigma

  int c0 = tid, c1 = tid + 256;
  const float* qrow = qx + ((size_t)b * PP + p) * CC;
  const float* wrow = w + (size_t)p * CC;
  float t0 = (qrow[c0] * inv_sa - wrow[c0]) * rsig;
  float t1 = (qrow[c1] * inv_sa - wrow[c1]) * rsig;

  float nr = t0 * t0 + t1 * t1;
#pragma unroll
  for (int off = 32; off; off >>= 1) nr += __shfl_down(nr, off);
  __shared__ float red[4];
  if (lane == 0) red[wave] = nr;
  __syncthreads();
  float norm2 = red[0] + red[1] + red[2] + red[3];
  float scale = 1.f / fmaxf(sqrtf(norm2), 1e-12f);

  float* ob = out_t + (size_t)b * CC * PP + p;
  ob[(size_t)c0 * PP] = t0 * scale;
  ob[(size_t)c1 * PP] = t1 * scale;
}

// ---------------------------------------------------------------------------
extern "C" void kernel_launch(void* const* d_in, const int* in_sizes, int n_in,
                              void* d_out, int out_size, void* d_ws,
                              size_t ws_size, hipStream_t stream) {
  const float* x = (const float*)d_in[0];   // [B,C,H,W]
  const float* w = (const float*)d_in[1];   // [P,C,1,1]
  const float* sf = (const float*)d_in[2];  // [P]

  float* out_t = (float*)d_out;                         // [B,C,P]
  float* assign = out_t + (size_t)BB * CC * PP;         // [B,P,N]

  float* ws = (float*)d_ws;
  float* beta = ws;             // 32
  float* rbeta = ws + 32;       // 32
  float* csq = ws + 64;         // 32
  float* sum_ass = ws + 96;     // 512
  float* qx = ws + 608;         // B*P*C = 262144

  prep_kernel<<<PP, 64, 0, stream>>>(w, sf, beta, rbeta, csq);
  assign_kernel<<<BB * 16, 256, 0, stream>>>(x, w, rbeta, csq, assign);
  sum_ass_kernel<<<(BB * PP) / 4, 256, 0, stream>>>(assign, sum_ass);
  qx_kernel<<<dim3(CC / 4, BB), 256, 0, stream>>>(x, assign, qx);
  finalize_kernel<<<BB * PP, 256, 0, stream>>>(qx, w, beta, sum_ass, out_t);
}

// Round 2
// 122.584 us; speedup vs baseline: 2.7373x; 2.7373x over previous
//
#include <hip/hip_runtime.h>

constexpr int BB = 16;     // batch
constexpr int CC = 512;    // channels
constexpr int PP = 32;     // clusters
constexpr int NN = 4096;   // H*W

// ---------------------------------------------------------------------------
// prep: beta = sigmoid(sf), rbeta = 1/beta, csq[p] = |centers_p|^2
// ---------------------------------------------------------------------------
__global__ __launch_bounds__(64) void prep_kernel(
    const float* __restrict__ w, const float* __restrict__ sf,
    float* __restrict__ beta, float* __restrict__ rbeta,
    float* __restrict__ csq) {
  int p = blockIdx.x;
  int t = threadIdx.x;
  float s = 0.f;
  for (int i = t; i < CC; i += 64) {
    float v = w[p * CC + i];
    s = fmaf(v, v, s);
  }
#pragma unroll
  for (int off = 32; off; off >>= 1) s += __shfl_down(s, off);
  if (t == 0) {
    csq[p] = s;
    float e = __expf(-sf[p]);
    rbeta[p] = 1.f + e;            // 1/beta
    beta[p] = 1.f / (1.f + e);     // beta
  }
}

// ---------------------------------------------------------------------------
// assign: 1024 blocks (b * 64 n-tiles of 64 px), 256 thr = 4 waves.
// wave wv owns p in [8wv, 8wv+8). centers chunk-staged in LDS (broadcast
// reads); x read from global (coalesced dword, L1-shared across waves).
// Cross-wave softmax via small LDS reduce. Writes assign [B,P,N].
// ---------------------------------------------------------------------------
__global__ __launch_bounds__(256) void assign_kernel(
    const float* __restrict__ x, const float* __restrict__ w,
    const float* __restrict__ rbeta, const float* __restrict__ csq,
    float* __restrict__ assign_out) {
  __shared__ float cs[64][36];      // [c][p] pad 36 -> 9.2 KB
  __shared__ float red[2][4][64];   // softmax partials

  int tid = threadIdx.x;
  int wv = tid >> 6, lane = tid & 63;
  int b = blockIdx.x >> 6;
  int n0 = (blockIdx.x & 63) << 6;
  const float* xb = x + (size_t)b * CC * NN + n0 + lane;

  int sp = tid >> 3;            // staging p row 0..31
  int sk = (tid & 7) << 2;      // staging c quad 0..28

  float acc[8];
#pragma unroll
  for (int j = 0; j < 8; ++j) acc[j] = 0.f;
  float xsq = 0.f;

  for (int c0 = 0; c0 < CC; c0 += 64) {
    float4 v0 = *(const float4*)&w[(size_t)sp * CC + c0 + sk];
    float4 v1 = *(const float4*)&w[(size_t)sp * CC + c0 + sk + 32];
    __syncthreads();  // previous chunk's readers done
    cs[sk + 0][sp] = v0.x; cs[sk + 1][sp] = v0.y;
    cs[sk + 2][sp] = v0.z; cs[sk + 3][sp] = v0.w;
    cs[sk + 32][sp] = v1.x; cs[sk + 33][sp] = v1.y;
    cs[sk + 34][sp] = v1.z; cs[sk + 35][sp] = v1.w;
    __syncthreads();
#pragma unroll 8
    for (int c = 0; c < 64; ++c) {
      float xv = xb[(size_t)(c0 + c) * NN];
      xsq = fmaf(xv, xv, xsq);
      float4 ca = *(const float4*)&cs[c][wv * 8];      // broadcast
      float4 cb = *(const float4*)&cs[c][wv * 8 + 4];  // broadcast
      acc[0] = fmaf(ca.x, xv, acc[0]);
      acc[1] = fmaf(ca.y, xv, acc[1]);
      acc[2] = fmaf(ca.z, xv, acc[2]);
      acc[3] = fmaf(ca.w, xv, acc[3]);
      acc[4] = fmaf(cb.x, xv, acc[4]);
      acc[5] = fmaf(cb.y, xv, acc[5]);
      acc[6] = fmaf(cb.z, xv, acc[6]);
      acc[7] = fmaf(cb.w, xv, acc[7]);
    }
  }

  // logits for this wave's 8 p's
  float lg[8], m = -3.4e38f;
#pragma unroll
  for (int j = 0; j < 8; ++j) {
    int p = wv * 8 + j;
    lg[j] = fminf(2.f * acc[j] - xsq - csq[p], 0.f) * rbeta[p];
    m = fmaxf(m, lg[j]);
  }
  __syncthreads();
  red[0][wv][lane] = m;
  __syncthreads();
  m = fmaxf(fmaxf(red[0][0][lane], red[0][1][lane]),
            fmaxf(red[0][2][lane], red[0][3][lane]));
  float s = 0.f;
#pragma unroll
  for (int j = 0; j < 8; ++j) {
    lg[j] = __expf(lg[j] - m);
    s += lg[j];
  }
  __syncthreads();
  red[1][wv][lane] = s;
  __syncthreads();
  s = red[1][0][lane] + red[1][1][lane] + red[1][2][lane] + red[1][3][lane];
  float inv = 1.f / s;
  float* ao = assign_out + ((size_t)b * PP + wv * 8) * NN + n0 + lane;
#pragma unroll
  for (int j = 0; j < 8; ++j) ao[(size_t)j * NN] = lg[j] * inv;
}

// ---------------------------------------------------------------------------
// sum_ass: sum over n of assign, clipped at 1e-5. one wave per (b,p).
// ---------------------------------------------------------------------------
__global__ __launch_bounds__(256) void sum_ass_kernel(
    const float* __restrict__ assign, float* __restrict__ sum_ass) {
  int wid = blockIdx.x * 4 + (threadIdx.x >> 6);
  int lane = threadIdx.x & 63;
  const float4* ap = (const float4*)(assign + (size_t)wid * NN);
  float s = 0.f;
#pragma unroll
  for (int i = 0; i < 16; ++i) {
    float4 v = ap[i * 64 + lane];
    s += (v.x + v.y) + (v.z + v.w);
  }
#pragma unroll
  for (int off = 32; off; off >>= 1) s += __shfl_down(s, off);
  if (lane == 0) sum_ass[wid] = fmaxf(s, 1e-5f);
}

// ---------------------------------------------------------------------------
// qx tiled GEMM: qx[b][p][c] = sum_k assign[b][p][k] * x[b][c][k]
// grid (32 = 8 kchunks x 4 ctiles, 16 b), block 256.
// Output tile 32p x 128c, K-chunk 512 in 8 staged steps of 64.
// xs transposed [k][c] (pad 132), as transposed [k][p] (pad 36).
// Partial results atomicAdd'ed into zeroed qx.
// ---------------------------------------------------------------------------
__global__ __launch_bounds__(256) void qx_kernel(
    const float* __restrict__ x, const float* __restrict__ assign,
    float* __restrict__ qx) {
  __shared__ float xs[64][132];   // 33 KB
  __shared__ float as[64][36];    // 9.2 KB

  int tid = threadIdx.x;
  int b = blockIdx.y;
  int kc = blockIdx.x >> 2;       // 0..7
  int ct = blockIdx.x & 3;        // 0..3
  const float* xb = x + ((size_t)b * CC + ct * 128) * NN + kc * 512;
  const float* ab = assign + (size_t)b * PP * NN + kc * 512;

  int cq = (tid & 31) << 2;       // compute c offset 0..124
  int pq = (tid >> 5) << 2;       // compute p offset 0..28
  int xk = tid & 63;              // staging: lane = k (coalesced global)
  int xc = tid >> 6;              // staging c-quad base 0..3
  int ap_ = tid >> 3;             // assign staging p 0..31
  int ak = (tid & 7) << 2;        // assign staging k quad 0..28

  float acc[16];
#pragma unroll
  for (int i = 0; i < 16; ++i) acc[i] = 0.f;

  for (int ks = 0; ks < 512; ks += 64) {
    // issue global loads early
    float xv[8][4];
#pragma unroll
    for (int pass = 0; pass < 8; ++pass) {
      int c4 = (xc + pass * 4) << 2;
#pragma unroll
      for (int i = 0; i < 4; ++i)
        xv[pass][i] = xb[(size_t)(c4 + i) * NN + ks + xk];
    }
    float4 a0 = *(const float4*)&ab[(size_t)ap_ * NN + ks + ak];
    float4 a1 = *(const float4*)&ab[(size_t)ap_ * NN + ks + ak + 32];
    __syncthreads();  // previous step's readers done
#pragma unroll
    for (int pass = 0; pass < 8; ++pass) {
      int c4 = (xc + pass * 4) << 2;
      *(float4*)&xs[xk][c4] =
          make_float4(xv[pass][0], xv[pass][1], xv[pass][2], xv[pass][3]);
    }
    as[ak + 0][ap_] = a0.x; as[ak + 1][ap_] = a0.y;
    as[ak + 2][ap_] = a0.z; as[ak + 3][ap_] = a0.w;
    as[ak + 32][ap_] = a1.x; as[ak + 33][ap_] = a1.y;
    as[ak + 34][ap_] = a1.z; as[ak + 35][ap_] = a1.w;
    __syncthreads();
#pragma unroll 8
    for (int k = 0; k < 64; ++k) {
      float4 xvv = *(const float4*)&xs[k][cq];
      float4 avv = *(const float4*)&as[k][pq];  // broadcast
      acc[0]  = fmaf(avv.x, xvv.x, acc[0]);
      acc[1]  = fmaf(avv.x, xvv.y, acc[1]);
      acc[2]  = fmaf(avv.x, xvv.z, acc[2]);
      acc[3]  = fmaf(avv.x, xvv.w, acc[3]);
      acc[4]  = fmaf(avv.y, xvv.x, acc[4]);
      acc[5]  = fmaf(avv.y, xvv.y, acc[5]);
      acc[6]  = fmaf(avv.y, xvv.z, acc[6]);
      acc[7]  = fmaf(avv.y, xvv.w, acc[7]);
      acc[8]  = fmaf(avv.z, xvv.x, acc[8]);
      acc[9]  = fmaf(avv.z, xvv.y, acc[9]);
      acc[10] = fmaf(avv.z, xvv.z, acc[10]);
      acc[11] = fmaf(avv.z, xvv.w, acc[11]);
      acc[12] = fmaf(avv.w, xvv.x, acc[12]);
      acc[13] = fmaf(avv.w, xvv.y, acc[13]);
      acc[14] = fmaf(avv.w, xvv.z, acc[14]);
      acc[15] = fmaf(avv.w, xvv.w, acc[15]);
    }
  }

#pragma unroll
  for (int i = 0; i < 4; ++i) {
    float* q = qx + ((size_t)b * PP + pq + i) * CC + ct * 128 + cq;
#pragma unroll
    for (int j = 0; j < 4; ++j) atomicAdd(&q[j], acc[i * 4 + j]);
  }
}

// ---------------------------------------------------------------------------
// finalize: out = (qx/sum_ass - centers)/sigma ; L2-normalize over c;
// write transposed out_t[b][c][p]. block per (b,p), 256 threads, 2 c each.
// ---------------------------------------------------------------------------
__global__ __launch_bounds__(256) void finalize_kernel(
    const float* __restrict__ qx, const float* __restrict__ w,
    const float* __restrict__ beta, const float* __restrict__ sum_ass,
    float* __restrict__ out_t) {
  int b = blockIdx.x >> 5;
  int p = blockIdx.x & 31;
  int tid = threadIdx.x;
  int wave = tid >> 6, lane = tid & 63;

  float inv_sa = 1.f / sum_ass[b * PP + p];
  float rsig = rsqrtf(0.5f * beta[p]);

  int c0 = tid, c1 = tid + 256;
  const float* qrow = qx + ((size_t)b * PP + p) * CC;
  const float* wrow = w + (size_t)p * CC;
  float t0 = (qrow[c0] * inv_sa - wrow[c0]) * rsig;
  float t1 = (qrow[c1] * inv_sa - wrow[c1]) * rsig;

  float nr = t0 * t0 + t1 * t1;
#pragma unroll
  for (int off = 32; off; off >>= 1) nr += __shfl_down(nr, off);
  __shared__ float red[4];
  if (lane == 0) red[wave] = nr;
  __syncthreads();
  float norm2 = red[0] + red[1] + red[2] + red[3];
  float scale = 1.f / fmaxf(sqrtf(norm2), 1e-12f);

  float* ob = out_t + (size_t)b * CC * PP + p;
  ob[(size_t)c0 * PP] = t0 * scale;
  ob[(size_t)c1 * PP] = t1 * scale;
}

// ---------------------------------------------------------------------------
extern "C" void kernel_launch(void* const* d_in, const int* in_sizes, int n_in,
                              void* d_out, int out_size, void* d_ws,
                              size_t ws_size, hipStream_t stream) {
  const float* x = (const float*)d_in[0];   // [B,C,H,W]
  const float* w = (const float*)d_in[1];   // [P,C,1,1]
  const float* sf = (const float*)d_in[2];  // [P]

  float* out_t = (float*)d_out;                  // [B,C,P]
  float* assign = out_t + (size_t)BB * CC * PP;  // [B,P,N]

  float* ws = (float*)d_ws;
  float* beta = ws;           // 32
  float* rbeta = ws + 32;     // 32
  float* csq = ws + 64;       // 32
  float* sum_ass = ws + 96;   // 512
  float* qx = ws + 608;       // B*P*C = 262144

  hipMemsetAsync(qx, 0, (size_t)BB * PP * CC * sizeof(float), stream);
  prep_kernel<<<PP, 64, 0, stream>>>(w, sf, beta, rbeta, csq);
  assign_kernel<<<BB * 64, 256, 0, stream>>>(x, w, rbeta, csq, assign);
  sum_ass_kernel<<<(BB * PP) / 4, 256, 0, stream>>>(assign, sum_ass);
  qx_kernel<<<dim3(32, BB), 256, 0, stream>>>(x, assign, qx);
  finalize_kernel<<<BB * PP, 256, 0, stream>>>(qx, w, beta, sum_ass, out_t);
}